// Round 3
// baseline (169.523 us; speedup 1.0000x reference)
//
#include <hip/hip_runtime.h>
#include <math.h>

#define LN_EPS 1e-5f

// Problem: B=8 scenes, A=16 agents, L=80 lanes, D=128, H=6.
// N=768 nodes (128 agents first), 96 nodes/scene, dense per-scene attention.
//
// SINGLE plain kernel (no cooperative launch), 168 blocks x 512 threads,
// 159.7 KB LDS -> 1 block/CU -> all 168 blocks co-resident (168 <= 256 CUs),
// so the DIY device-scope spin barriers below cannot deadlock: the HW
// dispatches every workgroup immediately at launch.
//   Phase A (168 blocks, 256 active th): V = relu(nodes@Wv) [tiles 0..143],
//            Qb = agents@Wq [tiles 144..167]  (round-2 proven 64x64 GEMM)
//   global barrier (atomicAdd + spin; input-only staging hidden under wait)
//   Phase B (blocks 0..95 = scene,head,half): stage Ns/Wk/Vh/Qs;
//            T = Q@Wk^T; S = T@Ns^T; softmax; O = P@Vh -> AO
//            (Sm stored TRANSPOSED [j][i] so PV reads P as f4)
//   scene barrier (12 signers per scene)
//   Phase C (blocks r12<8, 2 agents each): y1 = relu(AO@Wout1) 16-way
//            split-K, y2+base fused (Wout2,W1), LN, relu, @W2, relu+residual.
// ws floats: V[768][768] | Qb[128][768] | AO[128][768] | counters (int[16])

union SmemU {
    struct {                       // Phase A: 69,632 B
        float As[128][68];         // [k][row]
        float Bs[128][68];         // [k][col]
    } a;
    struct {                       // Phase B: 159,744 B
        float Ns[96][132];         // raw nodes               50688
        float Wks[128][132];       // Wk head-slice (Sm alias) 67584
        float Vh[96][64];          // V half-slice             24576
        float Qs[16][132];         // Q rows                    8448
        float Tt[16][132];         // T = Q@Wk_h^T              8448
    } b;
    struct {                       // Phase C: 25,632 B
        float ao0[768], ao1[768];
        float nr0[128], nr1[128];
        float ps0[2048], ps1[2048];
        float y10[128], y11[128];
        float hb0[128], hb1[128];
        float red[8];
    } c;
};

__global__ __launch_bounds__(512) void k_all(
    const float* __restrict__ agents, const float* __restrict__ lanes,
    const float* __restrict__ Wq, const float* __restrict__ Wk,
    const float* __restrict__ Wv, const float* __restrict__ Wout1,
    const float* __restrict__ Wout2, const float* __restrict__ W1,
    const float* __restrict__ ln_g, const float* __restrict__ ln_b,
    const float* __restrict__ W2, float* __restrict__ V,
    float* __restrict__ Qb, float* __restrict__ AO,
    int* __restrict__ cnts, float* __restrict__ out)
{
    __shared__ SmemU sm;
    const int tid = threadIdx.x;
    const int bid = blockIdx.x;

    // ======================= Phase A: V / Qb GEMM =======================
    if (tid < 256) {
        const float* W;
        float* Out;
        int r0, wc0;
        bool dorelu = false;
        if (bid < 144) {
            const int br = bid % 12, bc = bid / 12;
            r0 = br * 64; W = Wv; wc0 = bc * 64; Out = V; dorelu = true;
        } else {
            const int idx = bid - 144;
            r0 = (idx & 1) * 64; W = Wq; wc0 = (idx >> 1) * 64; Out = Qb;
        }
        {   // stage A-tile (64 rows x 128 k) transposed
            const int row = tid >> 2, kv = tid & 3;
            const int gr = r0 + row;
            const float* src = (gr < 128) ? (agents + (size_t)gr * 128)
                                          : (lanes + (size_t)(gr - 128) * 128);
            #pragma unroll
            for (int j = 0; j < 8; ++j) {
                const int k0 = kv * 4 + j * 16;
                const float4 a = *(const float4*)(src + k0);
                sm.a.As[k0 + 0][row] = a.x; sm.a.As[k0 + 1][row] = a.y;
                sm.a.As[k0 + 2][row] = a.z; sm.a.As[k0 + 3][row] = a.w;
            }
        }
        {   // stage B-tile (128 k x 64 cols)
            const int kr = tid >> 4, c4 = tid & 15;
            #pragma unroll
            for (int i = 0; i < 8; ++i) {
                const int k = kr + 16 * i;
                *(float4*)&sm.a.Bs[k][c4 * 4] =
                    *(const float4*)(W + (size_t)k * 768 + wc0 + c4 * 4);
            }
        }
        __syncthreads();
        const int tx = tid & 15, ty = tid >> 4;
        float acc[4][4] = {};
        #pragma unroll 8
        for (int k = 0; k < 128; ++k) {
            const float4 a = *(const float4*)&sm.a.As[k][ty * 4];
            const float4 b = *(const float4*)&sm.a.Bs[k][tx * 4];
            const float av[4] = {a.x, a.y, a.z, a.w};
            #pragma unroll
            for (int i = 0; i < 4; ++i) {
                acc[i][0] += av[i] * b.x; acc[i][1] += av[i] * b.y;
                acc[i][2] += av[i] * b.z; acc[i][3] += av[i] * b.w;
            }
        }
        #pragma unroll
        for (int i = 0; i < 4; ++i) {
            float4 v = make_float4(acc[i][0], acc[i][1], acc[i][2], acc[i][3]);
            if (dorelu) {
                v.x = fmaxf(v.x, 0.f); v.y = fmaxf(v.y, 0.f);
                v.z = fmaxf(v.z, 0.f); v.w = fmaxf(v.w, 0.f);
            }
            *(float4*)(Out + (size_t)(r0 + ty * 4 + i) * 768 + wc0 + tx * 4) = v;
        }
    } else {
        __syncthreads();   // pair with staging barrier above
    }

    // ---- sign global barrier (release: all stores device-visible first)
    __threadfence();
    __syncthreads();
    if (tid == 0) atomicAdd(&cnts[0], 1);
    if (bid >= 96) return;

    const int s = bid / 12, r12 = bid % 12;
    const int h = r12 >> 1, half = r12 & 1;

    // ---- input-only staging for phase B (no phase-A dependency): hidden
    //      under the barrier wait.
    #pragma unroll
    for (int ii = 0; ii < 6; ++ii) {
        const int idx = tid + ii * 512;          // Ns: 96 x 32 f4
        const int n = idx >> 5, c4 = idx & 31;
        const float* src = (n < 16) ? (agents + (size_t)(s * 16 + n) * 128)
                                    : (lanes + (size_t)(s * 80 + n - 16) * 128);
        *(float4*)&sm.b.Ns[n][c4 * 4] = *(const float4*)(src + c4 * 4);
    }
    #pragma unroll
    for (int ii = 0; ii < 8; ++ii) {
        const int idx = tid + ii * 512;          // Wks: 128 x 32 f4
        const int row = idx >> 5, c4 = idx & 31;
        *(float4*)&sm.b.Wks[row][c4 * 4] =
            *(const float4*)(Wk + (size_t)row * 768 + h * 128 + c4 * 4);
    }

    // ---- wait for phase A everywhere (V, Qb); safety-valve breaks the spin
    //      so a co-residency failure shows as a correctness fail, not a hang.
    if (tid == 0) {
        int guard = 0;
        while (atomicAdd(&cnts[0], 0) < 168 && guard < 10000000) {
            __builtin_amdgcn_s_sleep(2); ++guard;
        }
    }
    __syncthreads();
    __threadfence();   // acquire: invalidate stale cache before V/Qb reads

    // ---- dependent staging: V half-slice + Q rows
    #pragma unroll
    for (int ii = 0; ii < 3; ++ii) {
        const int idx = tid + ii * 512;          // Vh: 96 x 16 f4
        const int n = idx >> 4, c4 = idx & 15;
        const int g = (n < 16) ? (s * 16 + n) : (128 + s * 80 + (n - 16));
        *(float4*)&sm.b.Vh[n][c4 * 4] =
            *(const float4*)(V + (size_t)g * 768 + h * 128 + half * 64 + c4 * 4);
    }
    {
        const int r = tid >> 5, c4 = tid & 31;   // Qs: 16 x 32 f4
        *(float4*)&sm.b.Qs[r][c4 * 4] =
            *(const float4*)(Qb + (size_t)(s * 16 + r) * 768 + h * 128 + c4 * 4);
    }
    __syncthreads();

    // ---- T[r][k] = sum_c Q[r][c]*Wks[k][c]; 128 threads, 4r x 4k register tile
    if (tid < 128) {
        const int kc = tid & 31, rq = tid >> 5;
        float acc[4][4] = {};
        #pragma unroll 4
        for (int c4 = 0; c4 < 32; ++c4) {
            float4 q[4], w[4];
            #pragma unroll
            for (int u = 0; u < 4; ++u)
                q[u] = *(const float4*)&sm.b.Qs[rq + 4 * u][c4 * 4];
            #pragma unroll
            for (int u = 0; u < 4; ++u)
                w[u] = *(const float4*)&sm.b.Wks[kc + 32 * u][c4 * 4];
            #pragma unroll
            for (int ur = 0; ur < 4; ++ur)
                #pragma unroll
                for (int uk = 0; uk < 4; ++uk)
                    acc[ur][uk] += q[ur].x * w[uk].x + q[ur].y * w[uk].y
                                 + q[ur].z * w[uk].z + q[ur].w * w[uk].w;
        }
        #pragma unroll
        for (int ur = 0; ur < 4; ++ur)
            #pragma unroll
            for (int uk = 0; uk < 4; ++uk)
                sm.b.Tt[rq + 4 * ur][kc + 32 * uk] = acc[ur][uk];
    }
    __syncthreads();

    // ---- S = T @ Ns^T + softmax; Sm stored TRANSPOSED [j][i] (aliases Wks)
    float (*Sm)[20] = (float (*)[20])&sm.b.Wks[0][0];   // 96 x 20 = 7680 B
    if (tid < 128) {
        const int jc = tid & 31, iq = tid >> 5;
        float s0[4] = {}, s1[4] = {}, s2[4] = {};
        #pragma unroll 4
        for (int kk = 0; kk < 32; ++kk) {
            float4 t[4];
            #pragma unroll
            for (int u = 0; u < 4; ++u)
                t[u] = *(const float4*)&sm.b.Tt[iq + 4 * u][kk * 4];
            const float4 n0 = *(const float4*)&sm.b.Ns[jc][kk * 4];
            const float4 n1 = *(const float4*)&sm.b.Ns[jc + 32][kk * 4];
            const float4 n2 = *(const float4*)&sm.b.Ns[jc + 64][kk * 4];
            #pragma unroll
            for (int u = 0; u < 4; ++u) {
                s0[u] += t[u].x*n0.x + t[u].y*n0.y + t[u].z*n0.z + t[u].w*n0.w;
                s1[u] += t[u].x*n1.x + t[u].y*n1.y + t[u].z*n1.z + t[u].w*n1.w;
                s2[u] += t[u].x*n2.x + t[u].y*n2.y + t[u].z*n2.z + t[u].w*n2.w;
            }
        }
        const float scale = 0.088388347648318447f;   // 128^-0.5
        #pragma unroll
        for (int u = 0; u < 4; ++u) {
            const float a0 = s0[u] * scale, a1 = s1[u] * scale, a2 = s2[u] * scale;
            float m = fmaxf(fmaxf(a0, a1), a2);
            #pragma unroll
            for (int o = 16; o >= 1; o >>= 1) m = fmaxf(m, __shfl_xor(m, o, 32));
            const float e0 = __expf(a0 - m), e1 = __expf(a1 - m), e2 = __expf(a2 - m);
            float sum = e0 + e1 + e2;
            #pragma unroll
            for (int o = 16; o >= 1; o >>= 1) sum += __shfl_xor(sum, o, 32);
            const float inv = 1.0f / sum;
            const int i = iq + 4 * u;
            Sm[jc][i]      = e0 * inv;
            Sm[jc + 32][i] = e1 * inv;
            Sm[jc + 64][i] = e2 * inv;
        }
    }
    __syncthreads();

    // ---- O_half = P @ Vh; 64 threads, 4i x 4d; P read as f4 over i.
    if (tid < 64) {
        const int d4 = tid & 15, iq = tid >> 4;
        float4 acc[4] = {};
        #pragma unroll 2
        for (int j = 0; j < 96; ++j) {
            const float4 p = *(const float4*)&Sm[j][iq * 4];
            const float4 v = *(const float4*)&sm.b.Vh[j][d4 * 4];
            const float pv[4] = {p.x, p.y, p.z, p.w};
            #pragma unroll
            for (int u = 0; u < 4; ++u) {
                acc[u].x += pv[u] * v.x; acc[u].y += pv[u] * v.y;
                acc[u].z += pv[u] * v.z; acc[u].w += pv[u] * v.w;
            }
        }
        #pragma unroll
        for (int u = 0; u < 4; ++u)
            *(float4*)(AO + (size_t)(s * 16 + iq * 4 + u) * 768 +
                       h * 128 + half * 64 + d4 * 4) = acc[u];
    }

    // ---- sign scene barrier
    __threadfence();
    __syncthreads();
    if (tid == 0) atomicAdd(&cnts[1 + s], 1);
    if (r12 >= 8) return;

    if (tid == 0) {
        int guard = 0;
        while (atomicAdd(&cnts[1 + s], 0) < 12 && guard < 10000000) {
            __builtin_amdgcn_s_sleep(2); ++guard;
        }
    }
    __syncthreads();
    __threadfence();   // acquire before AO reads

    // ======================= Phase C: per-agent tail =======================
    const int a0 = s * 16 + r12 * 2, a1 = a0 + 1;
    if (tid < 192) {
        *(float4*)&sm.c.ao0[tid * 4] = *(const float4*)(AO + (size_t)a0 * 768 + tid * 4);
    } else if (tid < 384) {
        const int t = tid - 192;
        *(float4*)&sm.c.ao1[t * 4] = *(const float4*)(AO + (size_t)a1 * 768 + t * 4);
    } else if (tid < 416) {
        const int t = tid - 384;
        *(float4*)&sm.c.nr0[t * 4] = *(const float4*)(agents + (size_t)a0 * 128 + t * 4);
    } else if (tid < 448) {
        const int t = tid - 416;
        *(float4*)&sm.c.nr1[t * 4] = *(const float4*)(agents + (size_t)a1 * 128 + t * 4);
    }
    __syncthreads();

    const int d4 = tid & 31, g = tid >> 5;     // 16-way split-K, f4 across d
    {   // y1 = relu(ao @ Wout1), K=768 -> 48 k per group; weights shared x2
        float4 acc0 = make_float4(0, 0, 0, 0), acc1 = make_float4(0, 0, 0, 0);
        const int k0 = g * 48;
        #pragma unroll 8
        for (int k = 0; k < 48; ++k) {
            const float4 w = *(const float4*)(Wout1 + (size_t)(k0 + k) * 128 + d4 * 4);
            const float v0 = sm.c.ao0[k0 + k], v1 = sm.c.ao1[k0 + k];
            acc0.x += v0 * w.x; acc0.y += v0 * w.y; acc0.z += v0 * w.z; acc0.w += v0 * w.w;
            acc1.x += v1 * w.x; acc1.y += v1 * w.y; acc1.z += v1 * w.z; acc1.w += v1 * w.w;
        }
        *(float4*)&sm.c.ps0[g * 128 + d4 * 4] = acc0;
        *(float4*)&sm.c.ps1[g * 128 + d4 * 4] = acc1;
    }
    __syncthreads();
    if (tid < 128) {
        float u0 = 0.f, u1 = 0.f;
        #pragma unroll
        for (int gg = 0; gg < 16; ++gg) {
            u0 += sm.c.ps0[gg * 128 + tid]; u1 += sm.c.ps1[gg * 128 + tid];
        }
        sm.c.y10[tid] = fmaxf(u0, 0.f); sm.c.y11[tid] = fmaxf(u1, 0.f);
    }
    __syncthreads();
    {   // y2 + base fused: y1@Wout2 + agents@W1, K=128 -> 8 k per group
        float4 acc0 = make_float4(0, 0, 0, 0), acc1 = make_float4(0, 0, 0, 0);
        const int k0 = g * 8;
        #pragma unroll
        for (int k = 0; k < 8; ++k) {
            const float4 w2v = *(const float4*)(Wout2 + (size_t)(k0 + k) * 128 + d4 * 4);
            const float4 w1v = *(const float4*)(W1 + (size_t)(k0 + k) * 128 + d4 * 4);
            const float y0 = sm.c.y10[k0 + k], n0 = sm.c.nr0[k0 + k];
            const float y1 = sm.c.y11[k0 + k], n1 = sm.c.nr1[k0 + k];
            acc0.x += y0 * w2v.x + n0 * w1v.x; acc0.y += y0 * w2v.y + n0 * w1v.y;
            acc0.z += y0 * w2v.z + n0 * w1v.z; acc0.w += y0 * w2v.w + n0 * w1v.w;
            acc1.x += y1 * w2v.x + n1 * w1v.x; acc1.y += y1 * w2v.y + n1 * w1v.y;
            acc1.z += y1 * w2v.z + n1 * w1v.z; acc1.w += y1 * w2v.w + n1 * w1v.w;
        }
        *(float4*)&sm.c.ps0[g * 128 + d4 * 4] = acc0;
        *(float4*)&sm.c.ps1[g * 128 + d4 * 4] = acc1;
    }
    __syncthreads();
    float t0 = 0.f, t1 = 0.f;
    if (tid < 128) {
        #pragma unroll
        for (int gg = 0; gg < 16; ++gg) {
            t0 += sm.c.ps0[gg * 128 + tid]; t1 += sm.c.ps1[gg * 128 + tid];
        }
    }
    float s10 = t0, s20 = t0 * t0, s11 = t1, s21 = t1 * t1;
    #pragma unroll
    for (int o = 32; o >= 1; o >>= 1) {
        s10 += __shfl_xor(s10, o); s20 += __shfl_xor(s20, o);
        s11 += __shfl_xor(s11, o); s21 += __shfl_xor(s21, o);
    }
    if (tid < 128 && (tid & 63) == 0) {
        const int wid = tid >> 6;
        sm.c.red[wid * 4 + 0] = s10; sm.c.red[wid * 4 + 1] = s20;
        sm.c.red[wid * 4 + 2] = s11; sm.c.red[wid * 4 + 3] = s21;
    }
    __syncthreads();
    if (tid < 128) {
        const float S10 = sm.c.red[0] + sm.c.red[4], S20 = sm.c.red[1] + sm.c.red[5];
        const float S11 = sm.c.red[2] + sm.c.red[6], S21 = sm.c.red[3] + sm.c.red[7];
        const float mu0 = S10 * (1.0f / 128.0f);
        const float var0 = S20 * (1.0f / 128.0f) - mu0 * mu0;
        const float mu1 = S11 * (1.0f / 128.0f);
        const float var1 = S21 * (1.0f / 128.0f) - mu1 * mu1;
        const float g_ = ln_g[tid], b_ = ln_b[tid];
        sm.c.hb0[tid] = fmaxf((t0 - mu0) * rsqrtf(var0 + LN_EPS) * g_ + b_, 0.0f);
        sm.c.hb1[tid] = fmaxf((t1 - mu1) * rsqrtf(var1 + LN_EPS) * g_ + b_, 0.0f);
    }
    __syncthreads();
    {   // @W2, K=128
        float4 acc0 = make_float4(0, 0, 0, 0), acc1 = make_float4(0, 0, 0, 0);
        const int k0 = g * 8;
        #pragma unroll
        for (int k = 0; k < 8; ++k) {
            const float4 w = *(const float4*)(W2 + (size_t)(k0 + k) * 128 + d4 * 4);
            const float v0 = sm.c.hb0[k0 + k], v1 = sm.c.hb1[k0 + k];
            acc0.x += v0 * w.x; acc0.y += v0 * w.y; acc0.z += v0 * w.z; acc0.w += v0 * w.w;
            acc1.x += v1 * w.x; acc1.y += v1 * w.y; acc1.z += v1 * w.z; acc1.w += v1 * w.w;
        }
        *(float4*)&sm.c.ps0[g * 128 + d4 * 4] = acc0;
        *(float4*)&sm.c.ps1[g * 128 + d4 * 4] = acc1;
    }
    __syncthreads();
    if (tid < 128) {
        float o0 = sm.c.nr0[tid], o1 = sm.c.nr1[tid];
        #pragma unroll
        for (int gg = 0; gg < 16; ++gg) {
            o0 += sm.c.ps0[gg * 128 + tid]; o1 += sm.c.ps1[gg * 128 + tid];
        }
        out[(size_t)a0 * 128 + tid] = fmaxf(o0, 0.f);
        out[(size_t)a1 * 128 + tid] = fmaxf(o1, 0.f);
    }
}

// ---------------------------------------------------------------------------
extern "C" void kernel_launch(void* const* d_in, const int* in_sizes, int n_in,
                              void* d_out, int out_size, void* d_ws, size_t ws_size,
                              hipStream_t stream)
{
    const float* agents = (const float*)d_in[0];
    const float* lanes  = (const float*)d_in[1];
    const float* Wq     = (const float*)d_in[2];
    const float* Wk     = (const float*)d_in[3];
    const float* Wv     = (const float*)d_in[4];
    const float* Wout1  = (const float*)d_in[5];
    const float* Wout2  = (const float*)d_in[6];
    const float* W1     = (const float*)d_in[7];
    const float* ln_g   = (const float*)d_in[8];
    const float* ln_b   = (const float*)d_in[9];
    const float* W2     = (const float*)d_in[10];
    // d_in[11], d_in[12] = hi, wi — static dense per-scene structure, unused.

    float* ws = (float*)d_ws;
    float* V    = ws;                   // [768][768]
    float* Qb   = V + 768 * 768;        // [128][768]
    float* AO   = Qb + 128 * 768;       // [128][768]
    int*   cnts = (int*)(AO + 128 * 768);  // [0]=global, [1..8]=per-scene
    float* outp = (float*)d_out;

    // zero barrier counters (workspace is poison-filled by the harness each
    // iteration; this memset is stream-ordered after that fill, before k_all)
    hipMemsetAsync(cnts, 0, 64, stream);
    k_all<<<168, 512, 0, stream>>>(agents, lanes, Wq, Wk, Wv, Wout1, Wout2,
                                   W1, ln_g, ln_b, W2, V, Qb, AO, cnts, outp);
}

// Round 4
// 113.100 us; speedup vs baseline: 1.4989x; 1.4989x over previous
//
#include <hip/hip_runtime.h>
#include <math.h>

#define LN_EPS 1e-5f

// Problem: B=8 scenes, A=16 agents, L=80 lanes, D=128, H=6.
// N=768 nodes (128 agents first), 96 nodes/scene, dense per-scene attention.
//
// 2 plain kernels, no grid-wide sync (R1/R3 proved in-kernel grid handoff
// costs 60-80us on multi-XCD gfx950 due to L2 writeback/invalidate):
//   k_attn: 96 blocks (scene,head,half) x 512. Stage Ns + Wk-slice + Wv-half
//           in one burst; waves 0-3 compute Vh=relu(Ns@Wvh) from LDS (VALU)
//           WHILE waves 4-7 compute Q=A@Wq streaming Wq from global (VMEM);
//           then T=Q@Wk^T, S=T@Ns^T, softmax, O=P@Vh -> AO.
//           V/Qb never touch HBM.
//   k_tail: 64 blocks x 2 agents (R3 phase-C proven code): y1=relu(AO@Wout1)
//           16-way split-K, y2+base fused (Wout2,W1), LN, relu, @W2,
//           relu + residual.
// ws floats: AO[128][768] only.

// ---------------------------------------------------------------------------
__global__ __launch_bounds__(512) void k_attn(
    const float* __restrict__ agents, const float* __restrict__ lanes,
    const float* __restrict__ Wq, const float* __restrict__ Wk,
    const float* __restrict__ Wv, float* __restrict__ AO)
{
    // 40384 floats = 161,536 B (<= 163,840)
    //   Ns  [96][132] @ 0       (12672 f)  raw nodes
    //   Wks [128][132]@ 12672   (16896 f)  Wk head-slice; Sm aliases after T
    //   Wvh [128][68] @ 29568   ( 8704 f)  Wv half-slice; Vh+Qs alias after
    //   Tt  [16][132] @ 38272   ( 2112 f)  T = Q@Wk^T (separate, no WAR)
    __shared__ float smem[40384];
    float (*Ns)[132]  = (float (*)[132])(smem);
    float (*Wks)[132] = (float (*)[132])(smem + 12672);
    float (*Wvh)[68]  = (float (*)[68]) (smem + 29568);
    float (*Tt)[132]  = (float (*)[132])(smem + 38272);
    float (*Vh)[68]   = (float (*)[68]) (smem + 29568);   // rows 0..95 of Wvh
    float (*Qs)[132]  = (float (*)[132])(smem + 36096);   // Wvh rows 96..127
    float (*Sm)[20]   = (float (*)[20]) (smem + 12672);   // aliases Wks

    const int tid = threadIdx.x;
    const int b = blockIdx.x;
    const int s = b / 12, r12 = b % 12;
    const int h = r12 >> 1, half = r12 & 1;

    // ---- one burst: Ns (6 f4/th) + Wks (8 f4/th) + Wvh (4 f4/th)
    #pragma unroll
    for (int ii = 0; ii < 6; ++ii) {
        const int idx = tid + ii * 512;          // 96 x 32 f4
        const int n = idx >> 5, c4 = idx & 31;
        const float* src = (n < 16) ? (agents + (size_t)(s * 16 + n) * 128)
                                    : (lanes + (size_t)(s * 80 + n - 16) * 128);
        *(float4*)&Ns[n][c4 * 4] = *(const float4*)(src + c4 * 4);
    }
    #pragma unroll
    for (int ii = 0; ii < 8; ++ii) {
        const int idx = tid + ii * 512;          // 128 x 32 f4
        const int row = idx >> 5, c4 = idx & 31;
        *(float4*)&Wks[row][c4 * 4] =
            *(const float4*)(Wk + (size_t)row * 768 + h * 128 + c4 * 4);
    }
    #pragma unroll
    for (int ii = 0; ii < 4; ++ii) {
        const int idx = tid + ii * 512;          // 128 x 16 f4
        const int row = idx >> 4, c4 = idx & 15;
        *(float4*)&Wvh[row][c4 * 4] =
            *(const float4*)(Wv + (size_t)row * 768 + h * 128 + half * 64 + c4 * 4);
    }
    __syncthreads();

    // ---- wave-split: Vh (LDS/VALU, waves 0-3) || Q (global/VMEM, waves 4-7)
    float4 vacc[6];
    float4 qacc0 = make_float4(0, 0, 0, 0), qacc1 = make_float4(0, 0, 0, 0);
    int vr = 0, vc4 = 0, qc = 0, qrg = 0;
    if (tid < 256) {
        // Vh[96][64] = relu(Ns @ Wvh): thread owns rows {vr+16u}, col-f4 vc4
        vc4 = tid & 15; vr = tid >> 4;
        #pragma unroll
        for (int u = 0; u < 6; ++u) vacc[u] = make_float4(0, 0, 0, 0);
        #pragma unroll 2
        for (int k4 = 0; k4 < 32; ++k4) {
            float4 w[4];
            #pragma unroll
            for (int j = 0; j < 4; ++j)
                w[j] = *(const float4*)&Wvh[k4 * 4 + j][vc4 * 4];
            #pragma unroll
            for (int u = 0; u < 6; ++u) {
                const float4 nv = *(const float4*)&Ns[vr + 16 * u][k4 * 4];
                vacc[u].x += nv.x*w[0].x + nv.y*w[1].x + nv.z*w[2].x + nv.w*w[3].x;
                vacc[u].y += nv.x*w[0].y + nv.y*w[1].y + nv.z*w[2].y + nv.w*w[3].y;
                vacc[u].z += nv.x*w[0].z + nv.y*w[1].z + nv.z*w[2].z + nv.w*w[3].z;
                vacc[u].w += nv.x*w[0].w + nv.y*w[1].w + nv.z*w[2].w + nv.w*w[3].w;
            }
        }
    } else {
        // Q[16][128] = A_s @ Wq_head: thread owns rows {2qrg, 2qrg+1}, col-f4 qc
        const int t = tid - 256;
        qc = t & 31; qrg = t >> 5;
        const float* wp = Wq + (size_t)h * 128 + qc * 4;
        #pragma unroll 2
        for (int k4 = 0; k4 < 32; ++k4) {
            float4 w[4];
            #pragma unroll
            for (int j = 0; j < 4; ++j)
                w[j] = *(const float4*)(wp + (size_t)(k4 * 4 + j) * 768);
            const float4 n0 = *(const float4*)&Ns[2 * qrg][k4 * 4];
            const float4 n1 = *(const float4*)&Ns[2 * qrg + 1][k4 * 4];
            qacc0.x += n0.x*w[0].x + n0.y*w[1].x + n0.z*w[2].x + n0.w*w[3].x;
            qacc0.y += n0.x*w[0].y + n0.y*w[1].y + n0.z*w[2].y + n0.w*w[3].y;
            qacc0.z += n0.x*w[0].z + n0.y*w[1].z + n0.z*w[2].z + n0.w*w[3].z;
            qacc0.w += n0.x*w[0].w + n0.y*w[1].w + n0.z*w[2].w + n0.w*w[3].w;
            qacc1.x += n1.x*w[0].x + n1.y*w[1].x + n1.z*w[2].x + n1.w*w[3].x;
            qacc1.y += n1.x*w[0].y + n1.y*w[1].y + n1.z*w[2].y + n1.w*w[3].y;
            qacc1.z += n1.x*w[0].z + n1.y*w[1].z + n1.z*w[2].z + n1.w*w[3].z;
            qacc1.w += n1.x*w[0].w + n1.y*w[1].w + n1.z*w[2].w + n1.w*w[3].w;
        }
    }
    __syncthreads();   // all Wvh reads complete -> safe to overwrite with Vh/Qs

    if (tid < 256) {
        #pragma unroll
        for (int u = 0; u < 6; ++u) {
            float4 v = vacc[u];
            v.x = fmaxf(v.x, 0.f); v.y = fmaxf(v.y, 0.f);
            v.z = fmaxf(v.z, 0.f); v.w = fmaxf(v.w, 0.f);
            *(float4*)&Vh[vr + 16 * u][vc4 * 4] = v;
        }
    } else {
        *(float4*)&Qs[2 * qrg][qc * 4]     = qacc0;
        *(float4*)&Qs[2 * qrg + 1][qc * 4] = qacc1;
    }
    __syncthreads();

    // ---- T[r][k] = sum_c Q[r][c]*Wks[k][c]; 128 threads, 4r x 4k reg tile
    const int r = tid >> 5, kc = tid & 31;
    if (tid < 128) {
        float acc[4][4] = {};
        #pragma unroll 4
        for (int c4 = 0; c4 < 32; ++c4) {
            float4 q[4], w[4];
            #pragma unroll
            for (int u = 0; u < 4; ++u)
                q[u] = *(const float4*)&Qs[r + 4 * u][c4 * 4];
            #pragma unroll
            for (int u = 0; u < 4; ++u)
                w[u] = *(const float4*)&Wks[kc + 32 * u][c4 * 4];
            #pragma unroll
            for (int ur = 0; ur < 4; ++ur)
                #pragma unroll
                for (int uk = 0; uk < 4; ++uk)
                    acc[ur][uk] += q[ur].x * w[uk].x + q[ur].y * w[uk].y
                                 + q[ur].z * w[uk].z + q[ur].w * w[uk].w;
        }
        #pragma unroll
        for (int ur = 0; ur < 4; ++ur)
            #pragma unroll
            for (int uk = 0; uk < 4; ++uk)
                Tt[r + 4 * ur][kc + 32 * uk] = acc[ur][uk];   // separate buf
    }
    __syncthreads();

    // ---- S = T @ Ns^T + softmax; Sm stored TRANSPOSED [j][i] (aliases Wks)
    if (tid < 128) {
        const int jc = kc, iq = r;
        float s0[4] = {}, s1[4] = {}, s2[4] = {};
        #pragma unroll 4
        for (int kk = 0; kk < 32; ++kk) {
            float4 t[4];
            #pragma unroll
            for (int u = 0; u < 4; ++u)
                t[u] = *(const float4*)&Tt[iq + 4 * u][kk * 4];
            const float4 n0 = *(const float4*)&Ns[jc][kk * 4];
            const float4 n1 = *(const float4*)&Ns[jc + 32][kk * 4];
            const float4 n2 = *(const float4*)&Ns[jc + 64][kk * 4];
            #pragma unroll
            for (int u = 0; u < 4; ++u) {
                s0[u] += t[u].x*n0.x + t[u].y*n0.y + t[u].z*n0.z + t[u].w*n0.w;
                s1[u] += t[u].x*n1.x + t[u].y*n1.y + t[u].z*n1.z + t[u].w*n1.w;
                s2[u] += t[u].x*n2.x + t[u].y*n2.y + t[u].z*n2.z + t[u].w*n2.w;
            }
        }
        const float scale = 0.088388347648318447f;   // 128^-0.5
        #pragma unroll
        for (int u = 0; u < 4; ++u) {
            const float a0 = s0[u] * scale, a1 = s1[u] * scale, a2 = s2[u] * scale;
            float m = fmaxf(fmaxf(a0, a1), a2);
            #pragma unroll
            for (int o = 16; o >= 1; o >>= 1) m = fmaxf(m, __shfl_xor(m, o, 32));
            const float e0 = __expf(a0 - m), e1 = __expf(a1 - m), e2 = __expf(a2 - m);
            float sum = e0 + e1 + e2;
            #pragma unroll
            for (int o = 16; o >= 1; o >>= 1) sum += __shfl_xor(sum, o, 32);
            const float inv = 1.0f / sum;
            const int i = iq + 4 * u;
            Sm[jc][i]      = e0 * inv;
            Sm[jc + 32][i] = e1 * inv;
            Sm[jc + 64][i] = e2 * inv;
        }
    }
    __syncthreads();

    // ---- O_half = P @ Vh; 64 threads, 4i x 4d; P read as f4 over i.
    if (tid < 64) {
        const int d4 = tid & 15, iq = tid >> 4;
        float4 acc[4] = {};
        #pragma unroll 2
        for (int j = 0; j < 96; ++j) {
            const float4 p = *(const float4*)&Sm[j][iq * 4];
            const float4 v = *(const float4*)&Vh[j][d4 * 4];
            const float pv[4] = {p.x, p.y, p.z, p.w};
            #pragma unroll
            for (int u = 0; u < 4; ++u) {
                acc[u].x += pv[u] * v.x; acc[u].y += pv[u] * v.y;
                acc[u].z += pv[u] * v.z; acc[u].w += pv[u] * v.w;
            }
        }
        #pragma unroll
        for (int u = 0; u < 4; ++u)
            *(float4*)(AO + (size_t)(s * 16 + iq * 4 + u) * 768 +
                       h * 128 + half * 64 + d4 * 4) = acc[u];
    }
}

// ---------------------------------------------------------------------------
// Kernel 2: per-agent tail. 64 blocks x 2 agents (R3 phase-C proven code).
__global__ __launch_bounds__(512) void k_tail(
    const float* __restrict__ AO, const float* __restrict__ agents,
    const float* __restrict__ Wout1, const float* __restrict__ Wout2,
    const float* __restrict__ W1, const float* __restrict__ ln_g,
    const float* __restrict__ ln_b, const float* __restrict__ W2,
    float* __restrict__ out)
{
    __shared__ float ao0[768], ao1[768];
    __shared__ float nr0[128], nr1[128];
    __shared__ float ps0[2048], ps1[2048];
    __shared__ float y10[128], y11[128];
    __shared__ float hb0[128], hb1[128];
    __shared__ float red[8];

    const int tid = threadIdx.x;
    const int a0 = blockIdx.x * 2, a1 = a0 + 1;

    if (tid < 192) {
        *(float4*)&ao0[tid * 4] = *(const float4*)(AO + (size_t)a0 * 768 + tid * 4);
    } else if (tid < 384) {
        const int t = tid - 192;
        *(float4*)&ao1[t * 4] = *(const float4*)(AO + (size_t)a1 * 768 + t * 4);
    } else if (tid < 416) {
        const int t = tid - 384;
        *(float4*)&nr0[t * 4] = *(const float4*)(agents + (size_t)a0 * 128 + t * 4);
    } else if (tid < 448) {
        const int t = tid - 416;
        *(float4*)&nr1[t * 4] = *(const float4*)(agents + (size_t)a1 * 128 + t * 4);
    }
    __syncthreads();

    const int d4 = tid & 31, g = tid >> 5;     // 16-way split-K, f4 across d
    {   // y1 = relu(ao @ Wout1), K=768 -> 48 k per group; weights shared x2
        float4 acc0 = make_float4(0, 0, 0, 0), acc1 = make_float4(0, 0, 0, 0);
        const int k0 = g * 48;
        #pragma unroll 8
        for (int k = 0; k < 48; ++k) {
            const float4 w = *(const float4*)(Wout1 + (size_t)(k0 + k) * 128 + d4 * 4);
            const float v0 = ao0[k0 + k], v1 = ao1[k0 + k];
            acc0.x += v0 * w.x; acc0.y += v0 * w.y; acc0.z += v0 * w.z; acc0.w += v0 * w.w;
            acc1.x += v1 * w.x; acc1.y += v1 * w.y; acc1.z += v1 * w.z; acc1.w += v1 * w.w;
        }
        *(float4*)&ps0[g * 128 + d4 * 4] = acc0;
        *(float4*)&ps1[g * 128 + d4 * 4] = acc1;
    }
    __syncthreads();
    if (tid < 128) {
        float u0 = 0.f, u1 = 0.f;
        #pragma unroll
        for (int gg = 0; gg < 16; ++gg) {
            u0 += ps0[gg * 128 + tid]; u1 += ps1[gg * 128 + tid];
        }
        y10[tid] = fmaxf(u0, 0.f); y11[tid] = fmaxf(u1, 0.f);
    }
    __syncthreads();
    {   // y2 + base fused: y1@Wout2 + agents@W1, K=128 -> 8 k per group
        float4 acc0 = make_float4(0, 0, 0, 0), acc1 = make_float4(0, 0, 0, 0);
        const int k0 = g * 8;
        #pragma unroll
        for (int k = 0; k < 8; ++k) {
            const float4 w2v = *(const float4*)(Wout2 + (size_t)(k0 + k) * 128 + d4 * 4);
            const float4 w1v = *(const float4*)(W1 + (size_t)(k0 + k) * 128 + d4 * 4);
            const float v0 = y10[k0 + k], n0 = nr0[k0 + k];
            const float v1 = y11[k0 + k], n1 = nr1[k0 + k];
            acc0.x += v0 * w2v.x + n0 * w1v.x; acc0.y += v0 * w2v.y + n0 * w1v.y;
            acc0.z += v0 * w2v.z + n0 * w1v.z; acc0.w += v0 * w2v.w + n0 * w1v.w;
            acc1.x += v1 * w2v.x + n1 * w1v.x; acc1.y += v1 * w2v.y + n1 * w1v.y;
            acc1.z += v1 * w2v.z + n1 * w1v.z; acc1.w += v1 * w2v.w + n1 * w1v.w;
        }
        *(float4*)&ps0[g * 128 + d4 * 4] = acc0;
        *(float4*)&ps1[g * 128 + d4 * 4] = acc1;
    }
    __syncthreads();
    float t0 = 0.f, t1 = 0.f;
    if (tid < 128) {
        #pragma unroll
        for (int gg = 0; gg < 16; ++gg) {
            t0 += ps0[gg * 128 + tid]; t1 += ps1[gg * 128 + tid];
        }
    }
    float s10 = t0, s20 = t0 * t0, s11 = t1, s21 = t1 * t1;
    #pragma unroll
    for (int o = 32; o >= 1; o >>= 1) {
        s10 += __shfl_xor(s10, o); s20 += __shfl_xor(s20, o);
        s11 += __shfl_xor(s11, o); s21 += __shfl_xor(s21, o);
    }
    if (tid < 128 && (tid & 63) == 0) {
        const int wid = tid >> 6;
        red[wid * 4 + 0] = s10; red[wid * 4 + 1] = s20;
        red[wid * 4 + 2] = s11; red[wid * 4 + 3] = s21;
    }
    __syncthreads();
    if (tid < 128) {
        const float S10 = red[0] + red[4], S20 = red[1] + red[5];
        const float S11 = red[2] + red[6], S21 = red[3] + red[7];
        const float mu0 = S10 * (1.0f / 128.0f);
        const float var0 = S20 * (1.0f / 128.0f) - mu0 * mu0;
        const float mu1 = S11 * (1.0f / 128.0f);
        const float var1 = S21 * (1.0f / 128.0f) - mu1 * mu1;
        const float g_ = ln_g[tid], b_ = ln_b[tid];
        hb0[tid] = fmaxf((t0 - mu0) * rsqrtf(var0 + LN_EPS) * g_ + b_, 0.0f);
        hb1[tid] = fmaxf((t1 - mu1) * rsqrtf(var1 + LN_EPS) * g_ + b_, 0.0f);
    }
    __syncthreads();
    {   // @W2, K=128
        float4 acc0 = make_float4(0, 0, 0, 0), acc1 = make_float4(0, 0, 0, 0);
        const int k0 = g * 8;
        #pragma unroll
        for (int k = 0; k < 8; ++k) {
            const float4 w = *(const float4*)(W2 + (size_t)(k0 + k) * 128 + d4 * 4);
            const float v0 = hb0[k0 + k], v1 = hb1[k0 + k];
            acc0.x += v0 * w.x; acc0.y += v0 * w.y; acc0.z += v0 * w.z; acc0.w += v0 * w.w;
            acc1.x += v1 * w.x; acc1.y += v1 * w.y; acc1.z += v1 * w.z; acc1.w += v1 * w.w;
        }
        *(float4*)&ps0[g * 128 + d4 * 4] = acc0;
        *(float4*)&ps1[g * 128 + d4 * 4] = acc1;
    }
    __syncthreads();
    if (tid < 128) {
        float o0 = nr0[tid], o1 = nr1[tid];
        #pragma unroll
        for (int gg = 0; gg < 16; ++gg) {
            o0 += ps0[gg * 128 + tid]; o1 += ps1[gg * 128 + tid];
        }
        out[(size_t)a0 * 128 + tid] = fmaxf(o0, 0.f);
        out[(size_t)a1 * 128 + tid] = fmaxf(o1, 0.f);
    }
}

// ---------------------------------------------------------------------------
extern "C" void kernel_launch(void* const* d_in, const int* in_sizes, int n_in,
                              void* d_out, int out_size, void* d_ws, size_t ws_size,
                              hipStream_t stream)
{
    const float* agents = (const float*)d_in[0];
    const float* lanes  = (const float*)d_in[1];
    const float* Wq     = (const float*)d_in[2];
    const float* Wk     = (const float*)d_in[3];
    const float* Wv     = (const float*)d_in[4];
    const float* Wout1  = (const float*)d_in[5];
    const float* Wout2  = (const float*)d_in[6];
    const float* W1     = (const float*)d_in[7];
    const float* ln_g   = (const float*)d_in[8];
    const float* ln_b   = (const float*)d_in[9];
    const float* W2     = (const float*)d_in[10];
    // d_in[11], d_in[12] = hi, wi — static dense per-scene structure, unused.

    float* AO   = (float*)d_ws;        // [128][768] — only workspace use
    float* outp = (float*)d_out;

    k_attn<<<96, 512, 0, stream>>>(agents, lanes, Wq, Wk, Wv, AO);
    k_tail<<<64, 512, 0, stream>>>(AO, agents, Wout1, Wout2, W1,
                                   ln_g, ln_b, W2, outp);
}

// Round 5
// 112.146 us; speedup vs baseline: 1.5116x; 1.0085x over previous
//
#include <hip/hip_runtime.h>
#include <math.h>

#define LN_EPS 1e-5f

// Problem: B=8 scenes, A=16 agents, L=80 lanes, D=128, H=6.
// N=768 nodes (128 agents first), 96 nodes/scene, dense per-scene attention.
//
// 2 plain kernels. Partitioned by per-CU LDS-pipe cycles (ds_read_b128 = 12cy
// on ONE shared pipe/CU was the hidden cost of all prior attention kernels):
//  k1 (240 blocks x 256):
//    blocks 0..143  : V = relu(nodes@Wv), 64x64 tiles (proven k_qv code)
//    blocks 144..239: TS = (scene,head,rowhalf): stage Ns+Wq+Wk_lo; Q (128-th
//                     reg tiles); T in 2 k-halves with Wk_hi restage OVERLAPPED
//                     on idle threads; S + softmax -> normalized P rows to ws.
//    V-blocks and TS-blocks run on DIFFERENT CUs concurrently (240<=256).
//  k2 (64 blocks x 512, 2 agents each): PV reading V directly from global
//    (coalesced 768-float rows, j-split over 6 waves, each f4 feeds both
//    agents) + full tail: y1=relu(ao@Wout1) 16-way split-K, y2+base fused
//    (Wout2,W1), LN, relu, @W2, relu+residual. No AO round-trip.
// ws floats: V[768][768] | P[8][6][16][96]

__global__ __launch_bounds__(256) void k_stage1(
    const float* __restrict__ agents, const float* __restrict__ lanes,
    const float* __restrict__ Wq, const float* __restrict__ Wk,
    const float* __restrict__ Wv, float* __restrict__ V,
    float* __restrict__ P)
{
    // union via flat buffer: V-tile uses 17408 f; TS uses 40128 f (160,512 B)
    __shared__ float smem[40128];
    const int tid = threadIdx.x;
    const int bid = blockIdx.x;

    if (bid < 144) {
        // ================= V tile: 64x64, K=128 (proven) =================
        float (*As)[68] = (float (*)[68])(smem);          // [k][row]
        float (*Bs)[68] = (float (*)[68])(smem + 8704);   // [k][col]
        const int br = bid % 12, bc = bid / 12;
        const int r0 = br * 64, wc0 = bc * 64;

        {   // stage A (64 rows x 128 k) transposed
            const int row = tid >> 2, kv = tid & 3;
            const int gr = r0 + row;
            const float* src = (gr < 128) ? (agents + (size_t)gr * 128)
                                          : (lanes + (size_t)(gr - 128) * 128);
            #pragma unroll
            for (int j = 0; j < 8; ++j) {
                const int k0 = kv * 4 + j * 16;
                const float4 a = *(const float4*)(src + k0);
                As[k0 + 0][row] = a.x; As[k0 + 1][row] = a.y;
                As[k0 + 2][row] = a.z; As[k0 + 3][row] = a.w;
            }
        }
        {   // stage B (128 k x 64 cols)
            const int kr = tid >> 4, c4 = tid & 15;
            #pragma unroll
            for (int i = 0; i < 8; ++i) {
                const int k = kr + 16 * i;
                *(float4*)&Bs[k][c4 * 4] =
                    *(const float4*)(Wv + (size_t)k * 768 + wc0 + c4 * 4);
            }
        }
        __syncthreads();
        const int tx = tid & 15, ty = tid >> 4;
        float acc[4][4] = {};
        #pragma unroll 8
        for (int k = 0; k < 128; ++k) {
            const float4 a = *(const float4*)&As[k][ty * 4];
            const float4 b = *(const float4*)&Bs[k][tx * 4];
            const float av[4] = {a.x, a.y, a.z, a.w};
            #pragma unroll
            for (int i = 0; i < 4; ++i) {
                acc[i][0] += av[i] * b.x; acc[i][1] += av[i] * b.y;
                acc[i][2] += av[i] * b.z; acc[i][3] += av[i] * b.w;
            }
        }
        #pragma unroll
        for (int i = 0; i < 4; ++i) {
            float4 v = make_float4(acc[i][0], acc[i][1], acc[i][2], acc[i][3]);
            v.x = fmaxf(v.x, 0.f); v.y = fmaxf(v.y, 0.f);
            v.z = fmaxf(v.z, 0.f); v.w = fmaxf(v.w, 0.f);
            *(float4*)(V + (size_t)(r0 + ty * 4 + i) * 768 + wc0 + tx * 4) = v;
        }
        return;
    }

    // ==================== TS block: (scene, head, rowhalf) ====================
    const int idx = bid - 144;
    const int s = idx / 12, rr = idx % 12;
    const int h = rr >> 1, rh = rr & 1;

    float (*Ns)[132] = (float (*)[132])(smem);          // 96 rows  (12672 f)
    float (*WA)[132] = (float (*)[132])(smem + 12672);  // 128 rows (16896 f)
    float (*WB)[132] = (float (*)[132])(smem + 29568);  //  64 rows ( 8448 f)
    float (*Qs)[132] = (float (*)[132])(smem + 38016);  //   8 rows ( 1056 f)
    float (*Tt)[132] = (float (*)[132])(smem + 39072);  //   8 rows ( 1056 f)

    // ---- burst: Ns (3168 f4) + WA<-Wq slice (4096 f4) + WB<-Wk rows 0..63
    #pragma unroll
    for (int i = 0; i < 13; ++i) {
        const int id2 = tid + i * 256;
        if (id2 < 3168) {
            const int n = id2 >> 5, c4 = id2 & 31;
            const float* src = (n < 16) ? (agents + (size_t)(s * 16 + n) * 128)
                                        : (lanes + (size_t)(s * 80 + n - 16) * 128);
            *(float4*)&Ns[n][c4 * 4] = *(const float4*)(src + c4 * 4);
        }
    }
    #pragma unroll
    for (int i = 0; i < 16; ++i) {
        const int id2 = tid + i * 256;
        const int row = id2 >> 5, c4 = id2 & 31;
        *(float4*)&WA[row][c4 * 4] =
            *(const float4*)(Wq + (size_t)row * 768 + h * 128 + c4 * 4);
    }
    #pragma unroll
    for (int i = 0; i < 8; ++i) {
        const int id2 = tid + i * 256;
        const int row = id2 >> 5, c4 = id2 & 31;
        *(float4*)&WB[row][c4 * 4] =
            *(const float4*)(Wk + (size_t)row * 768 + h * 128 + c4 * 4);
    }
    __syncthreads();

    // ---- Q[8][128] = A_rows @ Wq_h ; 128 threads, 2 rows x 1 f4-col each
    if (tid < 128) {
        const int nc = tid & 31, rq = tid >> 5;    // rq 0..3
        const int ra = rh * 8 + rq * 2;
        float4 acc0 = make_float4(0, 0, 0, 0), acc1 = make_float4(0, 0, 0, 0);
        #pragma unroll 4
        for (int c4 = 0; c4 < 32; ++c4) {
            float4 w[4];
            #pragma unroll
            for (int j = 0; j < 4; ++j)
                w[j] = *(const float4*)&WA[c4 * 4 + j][nc * 4];
            const float4 a0 = *(const float4*)&Ns[ra][c4 * 4];
            const float4 a1 = *(const float4*)&Ns[ra + 1][c4 * 4];
            acc0.x += a0.x*w[0].x + a0.y*w[1].x + a0.z*w[2].x + a0.w*w[3].x;
            acc0.y += a0.x*w[0].y + a0.y*w[1].y + a0.z*w[2].y + a0.w*w[3].y;
            acc0.z += a0.x*w[0].z + a0.y*w[1].z + a0.z*w[2].z + a0.w*w[3].z;
            acc0.w += a0.x*w[0].w + a0.y*w[1].w + a0.z*w[2].w + a0.w*w[3].w;
            acc1.x += a1.x*w[0].x + a1.y*w[1].x + a1.z*w[2].x + a1.w*w[3].x;
            acc1.y += a1.x*w[0].y + a1.y*w[1].y + a1.z*w[2].y + a1.w*w[3].y;
            acc1.z += a1.x*w[0].z + a1.y*w[1].z + a1.z*w[2].z + a1.w*w[3].z;
            acc1.w += a1.x*w[0].w + a1.y*w[1].w + a1.z*w[2].w + a1.w*w[3].w;
        }
        *(float4*)&Qs[rq * 2][nc * 4]     = acc0;
        *(float4*)&Qs[rq * 2 + 1][nc * 4] = acc1;
    }
    __syncthreads();

    // ---- T_lo (threads 0..63) || stage Wk rows 64..127 into WA (64..255)
    if (tid < 64) {
        const int kc = tid & 15, rq = tid >> 4;    // 4k x 2r per thread
        float acc[2][4] = {};
        #pragma unroll 4
        for (int c4 = 0; c4 < 32; ++c4) {
            float4 w[4];
            #pragma unroll
            for (int j = 0; j < 4; ++j)
                w[j] = *(const float4*)&WB[kc * 4 + j][c4 * 4];
            const float4 a0 = *(const float4*)&Qs[rq * 2][c4 * 4];
            const float4 a1 = *(const float4*)&Qs[rq * 2 + 1][c4 * 4];
            #pragma unroll
            for (int j = 0; j < 4; ++j) {
                acc[0][j] += a0.x*w[j].x + a0.y*w[j].y + a0.z*w[j].z + a0.w*w[j].w;
                acc[1][j] += a1.x*w[j].x + a1.y*w[j].y + a1.z*w[j].z + a1.w*w[j].w;
            }
        }
        #pragma unroll
        for (int u = 0; u < 2; ++u)
            #pragma unroll
            for (int j = 0; j < 4; ++j)
                Tt[rq * 2 + u][kc * 4 + j] = acc[u][j];
    } else {
        const int t = tid - 64;
        #pragma unroll
        for (int i = 0; i < 11; ++i) {
            const int id2 = t + i * 192;
            if (id2 < 2048) {
                const int row = id2 >> 5, c4 = id2 & 31;
                *(float4*)&WA[row][c4 * 4] =
                    *(const float4*)(Wk + (size_t)(64 + row) * 768 + h * 128 + c4 * 4);
            }
        }
    }
    __syncthreads();

    // ---- T_hi (threads 0..63) from WA rows 0..63 (= Wk rows 64..127)
    if (tid < 64) {
        const int kc = tid & 15, rq = tid >> 4;
        float acc[2][4] = {};
        #pragma unroll 4
        for (int c4 = 0; c4 < 32; ++c4) {
            float4 w[4];
            #pragma unroll
            for (int j = 0; j < 4; ++j)
                w[j] = *(const float4*)&WA[kc * 4 + j][c4 * 4];
            const float4 a0 = *(const float4*)&Qs[rq * 2][c4 * 4];
            const float4 a1 = *(const float4*)&Qs[rq * 2 + 1][c4 * 4];
            #pragma unroll
            for (int j = 0; j < 4; ++j) {
                acc[0][j] += a0.x*w[j].x + a0.y*w[j].y + a0.z*w[j].z + a0.w*w[j].w;
                acc[1][j] += a1.x*w[j].x + a1.y*w[j].y + a1.z*w[j].z + a1.w*w[j].w;
            }
        }
        #pragma unroll
        for (int u = 0; u < 2; ++u)
            #pragma unroll
            for (int j = 0; j < 4; ++j)
                Tt[rq * 2 + u][64 + kc * 4 + j] = acc[u][j];
    }
    __syncthreads();

    // ---- S[8][96] = T @ Ns^T + softmax; 128 threads, 2i x 3j each
    if (tid < 128) {
        const int jc = tid & 31, iq = tid >> 5;
        float s0[2] = {}, s1[2] = {}, s2[2] = {};
        #pragma unroll 4
        for (int kk = 0; kk < 32; ++kk) {
            const float4 t0 = *(const float4*)&Tt[iq * 2][kk * 4];
            const float4 t1 = *(const float4*)&Tt[iq * 2 + 1][kk * 4];
            const float4 n0 = *(const float4*)&Ns[jc][kk * 4];
            const float4 n1 = *(const float4*)&Ns[jc + 32][kk * 4];
            const float4 n2 = *(const float4*)&Ns[jc + 64][kk * 4];
            s0[0] += t0.x*n0.x + t0.y*n0.y + t0.z*n0.z + t0.w*n0.w;
            s1[0] += t0.x*n1.x + t0.y*n1.y + t0.z*n1.z + t0.w*n1.w;
            s2[0] += t0.x*n2.x + t0.y*n2.y + t0.z*n2.z + t0.w*n2.w;
            s0[1] += t1.x*n0.x + t1.y*n0.y + t1.z*n0.z + t1.w*n0.w;
            s1[1] += t1.x*n1.x + t1.y*n1.y + t1.z*n1.z + t1.w*n1.w;
            s2[1] += t1.x*n2.x + t1.y*n2.y + t1.z*n2.z + t1.w*n2.w;
        }
        const float scale = 0.088388347648318447f;   // 128^-0.5
        #pragma unroll
        for (int u = 0; u < 2; ++u) {
            const float a0 = s0[u] * scale, a1 = s1[u] * scale, a2 = s2[u] * scale;
            float m = fmaxf(fmaxf(a0, a1), a2);
            #pragma unroll
            for (int o = 16; o >= 1; o >>= 1) m = fmaxf(m, __shfl_xor(m, o, 32));
            const float e0 = __expf(a0 - m), e1 = __expf(a1 - m), e2 = __expf(a2 - m);
            float sum = e0 + e1 + e2;
            #pragma unroll
            for (int o = 16; o >= 1; o >>= 1) sum += __shfl_xor(sum, o, 32);
            const float inv = 1.0f / sum;
            const int i = rh * 8 + iq * 2 + u;
            float* dst = P + ((size_t)((s * 6 + h) * 16 + i)) * 96;
            dst[jc]      = e0 * inv;
            dst[jc + 32] = e1 * inv;
            dst[jc + 64] = e2 * inv;
        }
    }
}

// ---------------------------------------------------------------------------
// Kernel 2: PV (V from global, coalesced) + per-agent tail. 64 blocks x 512.
__global__ __launch_bounds__(512) void k_tail2(
    const float* __restrict__ V, const float* __restrict__ P,
    const float* __restrict__ agents, const float* __restrict__ Wout1,
    const float* __restrict__ Wout2, const float* __restrict__ W1,
    const float* __restrict__ ln_g, const float* __restrict__ ln_b,
    const float* __restrict__ W2, float* __restrict__ out)
{
    __shared__ float SmL[12][96];          // P rows: [h*2+a][j]
    __shared__ float psv0[2][768], psv1[2][768];
    __shared__ float ao0[768], ao1[768];
    __shared__ float nr0[128], nr1[128];
    __shared__ float ps0[2048], ps1[2048];
    __shared__ float y10[128], y11[128], hb0[128], hb1[128];
    __shared__ float red[8];

    const int tid = threadIdx.x, b = blockIdx.x;
    const int s = b >> 3, pr = b & 7;
    const int a0 = s * 16 + pr * 2, a1 = a0 + 1;

    if (tid < 288) {                       // stage 12 P-rows (288 f4)
        const int row = tid / 24, c4 = tid % 24;
        const int h = row >> 1, aa = row & 1;
        *(float4*)&SmL[row][c4 * 4] = *(const float4*)(
            P + ((size_t)((s * 6 + h) * 16 + pr * 2 + aa)) * 96 + c4 * 4);
    } else if (tid < 320) {
        const int t = tid - 288;
        *(float4*)&nr0[t * 4] = *(const float4*)(agents + (size_t)a0 * 128 + t * 4);
    } else if (tid < 352) {
        const int t = tid - 320;
        *(float4*)&nr1[t * 4] = *(const float4*)(agents + (size_t)a1 * 128 + t * 4);
    }
    __syncthreads();

    // ---- PV: 384 threads = (jhalf 2) x (head 6) x (c4 32); V f4 feeds both agents
    if (tid < 384) {
        const int c4 = tid & 31, hh = (tid >> 5) % 6, jh = tid / 192;
        const int col = hh * 128 + c4 * 4;
        float4 acc0 = make_float4(0, 0, 0, 0), acc1 = make_float4(0, 0, 0, 0);
        const int j0 = jh * 48;
        #pragma unroll 4
        for (int j = j0; j < j0 + 48; ++j) {
            const int row = (j < 16) ? (s * 16 + j) : (128 + s * 80 + j - 16);
            const float4 v = *(const float4*)(V + (size_t)row * 768 + col);
            const float p0 = SmL[hh * 2][j], p1 = SmL[hh * 2 + 1][j];
            acc0.x += p0 * v.x; acc0.y += p0 * v.y;
            acc0.z += p0 * v.z; acc0.w += p0 * v.w;
            acc1.x += p1 * v.x; acc1.y += p1 * v.y;
            acc1.z += p1 * v.z; acc1.w += p1 * v.w;
        }
        *(float4*)&psv0[jh][col] = acc0;
        *(float4*)&psv1[jh][col] = acc1;
    }
    __syncthreads();
    if (tid < 192) {                       // combine j-halves -> ao
        const float4 x0 = *(const float4*)&psv0[0][tid * 4];
        const float4 x1 = *(const float4*)&psv0[1][tid * 4];
        const float4 y0 = *(const float4*)&psv1[0][tid * 4];
        const float4 y1 = *(const float4*)&psv1[1][tid * 4];
        *(float4*)&ao0[tid * 4] = make_float4(x0.x + x1.x, x0.y + x1.y,
                                              x0.z + x1.z, x0.w + x1.w);
        *(float4*)&ao1[tid * 4] = make_float4(y0.x + y1.x, y0.y + y1.y,
                                              y0.z + y1.z, y0.w + y1.w);
    }
    __syncthreads();

    // ---- tail (proven R4 code)
    const int d4 = tid & 31, g = tid >> 5;     // 16-way split-K, f4 across d
    {   // y1 = relu(ao @ Wout1), K=768 -> 48 k per group; weights shared x2
        float4 acc0 = make_float4(0, 0, 0, 0), acc1 = make_float4(0, 0, 0, 0);
        const int k0 = g * 48;
        #pragma unroll 8
        for (int k = 0; k < 48; ++k) {
            const float4 w = *(const float4*)(Wout1 + (size_t)(k0 + k) * 128 + d4 * 4);
            const float v0 = ao0[k0 + k], v1 = ao1[k0 + k];
            acc0.x += v0 * w.x; acc0.y += v0 * w.y; acc0.z += v0 * w.z; acc0.w += v0 * w.w;
            acc1.x += v1 * w.x; acc1.y += v1 * w.y; acc1.z += v1 * w.z; acc1.w += v1 * w.w;
        }
        *(float4*)&ps0[g * 128 + d4 * 4] = acc0;
        *(float4*)&ps1[g * 128 + d4 * 4] = acc1;
    }
    __syncthreads();
    if (tid < 128) {
        float u0 = 0.f, u1 = 0.f;
        #pragma unroll
        for (int gg = 0; gg < 16; ++gg) {
            u0 += ps0[gg * 128 + tid]; u1 += ps1[gg * 128 + tid];
        }
        y10[tid] = fmaxf(u0, 0.f); y11[tid] = fmaxf(u1, 0.f);
    }
    __syncthreads();
    {   // y2 + base fused: y1@Wout2 + agents@W1, K=128 -> 8 k per group
        float4 acc0 = make_float4(0, 0, 0, 0), acc1 = make_float4(0, 0, 0, 0);
        const int k0 = g * 8;
        #pragma unroll
        for (int k = 0; k < 8; ++k) {
            const float4 w2v = *(const float4*)(Wout2 + (size_t)(k0 + k) * 128 + d4 * 4);
            const float4 w1v = *(const float4*)(W1 + (size_t)(k0 + k) * 128 + d4 * 4);
            const float v0 = y10[k0 + k], n0 = nr0[k0 + k];
            const float v1 = y11[k0 + k], n1 = nr1[k0 + k];
            acc0.x += v0 * w2v.x + n0 * w1v.x; acc0.y += v0 * w2v.y + n0 * w1v.y;
            acc0.z += v0 * w2v.z + n0 * w1v.z; acc0.w += v0 * w2v.w + n0 * w1v.w;
            acc1.x += v1 * w2v.x + n1 * w1v.x; acc1.y += v1 * w2v.y + n1 * w1v.y;
            acc1.z += v1 * w2v.z + n1 * w1v.z; acc1.w += v1 * w2v.w + n1 * w1v.w;
        }
        *(float4*)&ps0[g * 128 + d4 * 4] = acc0;
        *(float4*)&ps1[g * 128 + d4 * 4] = acc1;
    }
    __syncthreads();
    float t0 = 0.f, t1 = 0.f;
    if (tid < 128) {
        #pragma unroll
        for (int gg = 0; gg < 16; ++gg) {
            t0 += ps0[gg * 128 + tid]; t1 += ps1[gg * 128 + tid];
        }
    }
    float s10 = t0, s20 = t0 * t0, s11 = t1, s21 = t1 * t1;
    #pragma unroll
    for (int o = 32; o >= 1; o >>= 1) {
        s10 += __shfl_xor(s10, o); s20 += __shfl_xor(s20, o);
        s11 += __shfl_xor(s11, o); s21 += __shfl_xor(s21, o);
    }
    if (tid < 128 && (tid & 63) == 0) {
        const int wid = tid >> 6;
        red[wid * 4 + 0] = s10; red[wid * 4 + 1] = s20;
        red[wid * 4 + 2] = s11; red[wid * 4 + 3] = s21;
    }
    __syncthreads();
    if (tid < 128) {
        const float S10 = red[0] + red[4], S20 = red[1] + red[5];
        const float S11 = red[2] + red[6], S21 = red[3] + red[7];
        const float mu0 = S10 * (1.0f / 128.0f);
        const float var0 = S20 * (1.0f / 128.0f) - mu0 * mu0;
        const float mu1 = S11 * (1.0f / 128.0f);
        const float var1 = S21 * (1.0f / 128.0f) - mu1 * mu1;
        const float g_ = ln_g[tid], b_ = ln_b[tid];
        hb0[tid] = fmaxf((t0 - mu0) * rsqrtf(var0 + LN_EPS) * g_ + b_, 0.0f);
        hb1[tid] = fmaxf((t1 - mu1) * rsqrtf(var1 + LN_EPS) * g_ + b_, 0.0f);
    }
    __syncthreads();
    {   // @W2, K=128
        float4 acc0 = make_float4(0, 0, 0, 0), acc1 = make_float4(0, 0, 0, 0);
        const int k0 = g * 8;
        #pragma unroll
        for (int k = 0; k < 8; ++k) {
            const float4 w = *(const float4*)(W2 + (size_t)(k0 + k) * 128 + d4 * 4);
            const float v0 = hb0[k0 + k], v1 = hb1[k0 + k];
            acc0.x += v0 * w.x; acc0.y += v0 * w.y; acc0.z += v0 * w.z; acc0.w += v0 * w.w;
            acc1.x += v1 * w.x; acc1.y += v1 * w.y; acc1.z += v1 * w.z; acc1.w += v1 * w.w;
        }
        *(float4*)&ps0[g * 128 + d4 * 4] = acc0;
        *(float4*)&ps1[g * 128 + d4 * 4] = acc1;
    }
    __syncthreads();
    if (tid < 128) {
        float o0 = nr0[tid], o1 = nr1[tid];
        #pragma unroll
        for (int gg = 0; gg < 16; ++gg) {
            o0 += ps0[gg * 128 + tid]; o1 += ps1[gg * 128 + tid];
        }
        out[(size_t)a0 * 128 + tid] = fmaxf(o0, 0.f);
        out[(size_t)a1 * 128 + tid] = fmaxf(o1, 0.f);
    }
}

// ---------------------------------------------------------------------------
extern "C" void kernel_launch(void* const* d_in, const int* in_sizes, int n_in,
                              void* d_out, int out_size, void* d_ws, size_t ws_size,
                              hipStream_t stream)
{
    const float* agents = (const float*)d_in[0];
    const float* lanes  = (const float*)d_in[1];
    const float* Wq     = (const float*)d_in[2];
    const float* Wk     = (const float*)d_in[3];
    const float* Wv     = (const float*)d_in[4];
    const float* Wout1  = (const float*)d_in[5];
    const float* Wout2  = (const float*)d_in[6];
    const float* W1     = (const float*)d_in[7];
    const float* ln_g   = (const float*)d_in[8];
    const float* ln_b   = (const float*)d_in[9];
    const float* W2     = (const float*)d_in[10];
    // d_in[11], d_in[12] = hi, wi — static dense per-scene structure, unused.

    float* ws = (float*)d_ws;
    float* V    = ws;                   // [768][768]
    float* P    = V + 768 * 768;        // [8][6][16][96]
    float* outp = (float*)d_out;

    k_stage1<<<240, 256, 0, stream>>>(agents, lanes, Wq, Wk, Wv, V, P);
    k_tail2 <<<64, 512, 0, stream>>>(V, P, agents, Wout1, Wout2, W1,
                                     ln_g, ln_b, W2, outp);
}